// Round 7
// baseline (283.325 us; speedup 1.0000x reference)
//
#include <hip/hip_runtime.h>
#include <math.h>
#include <stdint.h>

#define N_NODES 32768
#define E_DIM   512
#define H_HEADS 8
#define D_HEAD  64
#define NNZ_E   524288

typedef __attribute__((ext_vector_type(4))) float f32x4;
typedef __attribute__((ext_vector_type(8))) _Float16 f16x8;  // 8 fp16 = 4 VGPRs

// async 16B global->LDS (wave-uniform LDS base + lane*16)
__device__ __forceinline__ void async16(const void* g, void* l) {
  __builtin_amdgcn_global_load_lds(
      (const __attribute__((address_space(1))) void*)g,
      (__attribute__((address_space(3))) void*)l, 16, 0, 0);
}

// 8-elem fp16 dot accumulated into f32 via v_dot2_f32_f16.
__device__ __forceinline__ float dot8(const f16x8 a, const f16x8 b, float acc) {
#if __has_builtin(__builtin_amdgcn_fdot2)
  acc = __builtin_amdgcn_fdot2(__builtin_shufflevector(a, a, 0, 1),
                               __builtin_shufflevector(b, b, 0, 1), acc, false);
  acc = __builtin_amdgcn_fdot2(__builtin_shufflevector(a, a, 2, 3),
                               __builtin_shufflevector(b, b, 2, 3), acc, false);
  acc = __builtin_amdgcn_fdot2(__builtin_shufflevector(a, a, 4, 5),
                               __builtin_shufflevector(b, b, 4, 5), acc, false);
  acc = __builtin_amdgcn_fdot2(__builtin_shufflevector(a, a, 6, 7),
                               __builtin_shufflevector(b, b, 6, 7), acc, false);
#else
#pragma unroll
  for (int i = 0; i < 8; ++i) acc = fmaf((float)a[i], (float)b[i], acc);
#endif
  return acc;
}

// ---------------------------------------------------------------------------
// prep_small (x pre-pass ELIMINATED — gemm consumes fp32 x directly):
//   blocks [0,128)    : q_w -> fp16 wq_h [512][512]
//   blocks [128,256)  : k_w -> fp16 wk_h
//   blocks [256,2304) : ge + CSR row_start
// Round-6 accounting showed ~75-100 us unattributed in prep+gemm; the 96 MB
// x round-trip (fp32 read + fp16 write + fp16 re-read) was redundant work.
// ---------------------------------------------------------------------------
__global__ __launch_bounds__(256) void prep_small(
    const float* __restrict__ q_w, const float* __restrict__ k_w,
    const int* __restrict__ row_index, const int* __restrict__ col_index,
    const int* __restrict__ to_col,
    _Float16* __restrict__ wq_h, _Float16* __restrict__ wk_h,
    int* __restrict__ row_start, int* __restrict__ ge) {
  const int b = blockIdx.x;
  if (b < 256) {
    const float* src = (b < 128) ? q_w : k_w;
    _Float16* dst = (b < 128) ? wq_h : wk_h;
    const int t = (b & 127) * 256 + threadIdx.x;
    const int r = t >> 6;            // 64 threads per 512-wide row
    const int c8 = (t & 63) << 3;    // 8 elements per thread
    const float4 v0 = *(const float4*)(src + (size_t)r * 512 + c8);
    const float4 v1 = *(const float4*)(src + (size_t)r * 512 + c8 + 4);
    f16x8 o;
    o[0] = (_Float16)v0.x; o[1] = (_Float16)v0.y;
    o[2] = (_Float16)v0.z; o[3] = (_Float16)v0.w;
    o[4] = (_Float16)v1.x; o[5] = (_Float16)v1.y;
    o[6] = (_Float16)v1.z; o[7] = (_Float16)v1.w;
    *(f16x8*)(dst + (size_t)r * 512 + c8) = o;
  } else {
    const int e = (b - 256) * 256 + threadIdx.x;
    if (e < NNZ_E) {
      ge[e] = to_col[col_index[e]];
      const int r0 = row_index[e];
      const int r1 = (e + 1 < NNZ_E) ? row_index[e + 1] : N_NODES;
      if (e == 0)
        for (int r = 0; r <= r0; ++r) row_start[r] = 0;
      for (int r = r0 + 1; r <= r1; ++r) row_start[r] = e + 1;
    }
  }
}

// ---------------------------------------------------------------------------
// fp16 MFMA GEMM, BK=32 (most-proven 2-barrier shape). A staged as RAW FP32
// via the round-0/2-proven ar/agc swizzle (16 KB tile), converted to fp16
// fragments IN-REGISTER (8 v_cvt per fragment, ~32 cvt/K-step — an order
// cheaper than the old split2 path). B is pre-converted fp16 (fcs map).
// Numerically identical to the xs-pre-split path (same RNE cvt, same MFMA
// order). XCD swizzle (b&7 = panel group) keeps the x panel HBM-once.
// Outputs fp16: qh = (x@qw+qb)/8 (head scale folded), kh = x@kw+kb.
// ---------------------------------------------------------------------------
__global__ __launch_bounds__(256) void gemm_mfma(
    const float* __restrict__ x,       // [N][512] fp32
    const _Float16* __restrict__ wqh,  // [512][512] fp16
    const _Float16* __restrict__ wkh,
    const float* __restrict__ q_b, const float* __restrict__ k_b,
    _Float16* __restrict__ qh, _Float16* __restrict__ kh) {
  __shared__ float Af[128 * 32];     // 16 KB fp32 A tile
  __shared__ _Float16 Bh[128 * 32];  // 8 KB fp16 B tile
  const int tid = threadIdx.x;
  const int w = tid >> 6;        // wave 0..3
  const int l = tid & 63;

  const int b = blockIdx.x;
  const int j = b >> 3;
  const int mb = (b & 7) * 32 + (j >> 3);
  const int c = j & 7;
  const bool is_q = ((c & 1) == 0);
  const int bm = mb * 128;
  const int bn = (c >> 1) * 128;

  const _Float16* __restrict__ wmat = is_q ? wqh : wkh;
  const float* __restrict__ bias = is_q ? q_b : k_b;
  _Float16* __restrict__ outp = is_q ? qh : kh;
  const float oscale = is_q ? 0.125f : 1.0f;

  const int wm = (w & 1) * 64;   // wave's m-quadrant
  const int wn = (w >> 1) * 64;  // wave's n-quadrant

  f32x4 acc[4][4];
#pragma unroll
  for (int i = 0; i < 4; ++i)
#pragma unroll
    for (int jj = 0; jj < 4; ++jj) acc[i][jj] = (f32x4){0.f, 0.f, 0.f, 0.f};

  // A staging (fp32): LDS float4-chunk jx of row r holds global chunk
  // jx^(r&7); lane l stages row l>>3, chunk (l&7)^(l>>3). [proven r0-r2]
  const int ar = l >> 3;
  const int agc = (l & 7) ^ ar;
  // B staging (fp16, r7 swizzle): LDS 8-elem chunk jx of row r holds global
  // chunk jx^((r>>1)&3); lane l covers row w*16+(l>>2), chunk l&3.
  const int sr0 = w * 16 + (l >> 2);
  const int sr1 = sr0 + 64;
  const int sc = (((l & 3) ^ ((l >> 3) & 3)) << 3);
  // fragment maps
  const int fr = l & 15;
  const int fcs = ((((l >> 4) ^ ((fr >> 1) & 3)) & 3) << 3);
  const int akc = (l >> 4) * 2;  // lane's global float4-chunk pair
  const int as = l & 7;          // row&7 XOR key (row = wm+i*16+fr)

  const _Float16* __restrict__ wa = wmat + (size_t)bn * 512;

  for (int k0 = 0; k0 < 512; k0 += 32) {
#pragma unroll
    for (int cc = 0; cc < 4; ++cc) {
      const int rbase = cc * 32 + w * 8;
      async16(x + (size_t)(bm + rbase + ar) * 512 + k0 + agc * 4,
              Af + rbase * 32);
    }
    async16(wa + (size_t)sr0 * 512 + k0 + sc, Bh + w * 512);
    async16(wa + (size_t)sr1 * 512 + k0 + sc, Bh + (w + 4) * 512);
    __syncthreads();

    f16x8 av[4], bv[4];
#pragma unroll
    for (int i = 0; i < 4; ++i) {
      const float* rp = Af + (wm + i * 16 + fr) * 32;
      const float4 fa = *(const float4*)(rp + ((akc ^ as) << 2));
      const float4 fb = *(const float4*)(rp + (((akc + 1) ^ as) << 2));
      f16x8 v;
      v[0] = (_Float16)fa.x; v[1] = (_Float16)fa.y;
      v[2] = (_Float16)fa.z; v[3] = (_Float16)fa.w;
      v[4] = (_Float16)fb.x; v[5] = (_Float16)fb.y;
      v[6] = (_Float16)fb.z; v[7] = (_Float16)fb.w;
      av[i] = v;
    }
#pragma unroll
    for (int i = 0; i < 4; ++i)
      bv[i] = *(const f16x8*)(Bh + (wn + i * 16 + fr) * 32 + fcs);
#pragma unroll
    for (int i = 0; i < 4; ++i)
#pragma unroll
      for (int jj = 0; jj < 4; ++jj)
        acc[i][jj] = __builtin_amdgcn_mfma_f32_16x16x32_f16(
            av[i], bv[jj], acc[i][jj], 0, 0, 0);
    __syncthreads();
  }

  // epilogue: C/D layout col = l&15 (n), row = (l>>4)*4 + reg (m); fp16 out
  const int cn = l & 15;
  const int cm4 = (l >> 4) * 4;
  float bvals[4];
#pragma unroll
  for (int jj = 0; jj < 4; ++jj) bvals[jj] = bias[bn + wn + jj * 16 + cn];
#pragma unroll
  for (int i = 0; i < 4; ++i) {
#pragma unroll
    for (int r = 0; r < 4; ++r) {
      const int m = bm + wm + i * 16 + cm4 + r;
      _Float16* op = outp + (size_t)m * 512 + bn + wn + cn;
#pragma unroll
      for (int jj = 0; jj < 4; ++jj) {
        op[jj * 16] = (_Float16)((acc[i][jj][r] + bvals[jj]) * oscale);
      }
    }
  }
}

// ---------------------------------------------------------------------------
// row_fused: CSR row-owned edge logits + online softmax + featurize.
// At its structural floor (~87 us): 512 MB logical k-gather, L2-miss path
// 286 MB @ 3.4 TB/s (round-6: removing half the VALU changed nothing).
// ---------------------------------------------------------------------------
__global__ __launch_bounds__(256) void row_fused(
    const _Float16* __restrict__ qh, const _Float16* __restrict__ kh,
    const int* __restrict__ row_start, const int* __restrict__ ge,
    const float* __restrict__ att_bias, const int* __restrict__ col_index,
    const float* __restrict__ dist, const float* __restrict__ pos,
    const float* __restrict__ col_pos, float* __restrict__ out) {
  const int r = blockIdx.x * 4 + (threadIdx.x >> 6);
  const int lane = threadIdx.x & 63;
  const int h = lane >> 3;
  const int start = row_start[r];
  const int end = row_start[r + 1];

  const f16x8 qv = *(const f16x8*)(qh + (size_t)r * E_DIM + lane * 8);
  const float* __restrict__ biasp = att_bias + (size_t)h * NNZ_E;

  float m = -INFINITY, l = 0.f, accw = 0.f, a0 = 0.f, a1 = 0.f, a2 = 0.f;

  auto edge_logit = [&](const f16x8 kv) -> float {
    float s = dot8(qv, kv, 0.f);
    s += __shfl_xor(s, 1);
    s += __shfl_xor(s, 2);
    s += __shfl_xor(s, 4);
    return s;
  };
  auto upd = [&](float logit, float dd, float c0, float c1, float c2) {
    const float w = (dd == 0.f) ? 0.f : __builtin_amdgcn_rcpf(dd);
    const float nm = fmaxf(m, logit);
    const float sc = __expf(m - nm);
    const float p = __expf(logit - nm);
    m = nm;
    l = fmaf(l, sc, p);
    const float pw = p * w;
    accw = fmaf(accw, sc, pw);
    a0 = fmaf(a0, sc, pw * c0);
    a1 = fmaf(a1, sc, pw * c1);
    a2 = fmaf(a2, sc, pw * c2);
  };

  int e = start;
  for (; e + 4 <= end; e += 4) {
    int g[4], cc[4];
    float dd[4], bb[4], cp[4][3];
    f16x8 kv[4];
#pragma unroll
    for (int i = 0; i < 4; ++i) g[i] = ge[e + i];
#pragma unroll
    for (int i = 0; i < 4; ++i)
      kv[i] = *(const f16x8*)(kh + (size_t)g[i] * E_DIM + lane * 8);
#pragma unroll
    for (int i = 0; i < 4; ++i) {
      cc[i] = col_index[e + i];
      dd[i] = dist[e + i];
      bb[i] = biasp[e + i];
    }
#pragma unroll
    for (int i = 0; i < 4; ++i) {
      cp[i][0] = col_pos[cc[i] * 3 + 0];
      cp[i][1] = col_pos[cc[i] * 3 + 1];
      cp[i][2] = col_pos[cc[i] * 3 + 2];
    }
    float s[4];
#pragma unroll
    for (int i = 0; i < 4; ++i) s[i] = edge_logit(kv[i]) + bb[i];
#pragma unroll
    for (int i = 0; i < 4; ++i) upd(s[i], dd[i], cp[i][0], cp[i][1], cp[i][2]);
  }
  for (; e < end; ++e) {
    const int g0 = ge[e];
    const f16x8 kv0 = *(const f16x8*)(kh + (size_t)g0 * E_DIM + lane * 8);
    const int c0 = col_index[e];
    const float dd0 = dist[e];
    const float bb0 = biasp[e];
    const float cp00 = col_pos[c0 * 3 + 0];
    const float cp01 = col_pos[c0 * 3 + 1];
    const float cp02 = col_pos[c0 * 3 + 2];
    const float s0 = edge_logit(kv0) + bb0;
    upd(s0, dd0, cp00, cp01, cp02);
  }

  if ((lane & 7) == 0) {
    const float invz = (l > 0.f) ? 1.f / l : 0.f;
    const float avg = accw * invz;
    const float v0 = a0 * invz - avg * pos[r * 3 + 0];
    const float v1 = a1 * invz - avg * pos[r * 3 + 1];
    const float v2 = a2 * invz - avg * pos[r * 3 + 2];
    const float nrm = sqrtf(v0 * v0 + v1 * v1 + v2 * v2);
    const float invn = 1.f / fmaxf(nrm, 1e-12f);
    float4 o;
    o.x = v0 * invn; o.y = v1 * invn; o.z = v2 * invn; o.w = avg;
    *(float4*)(out + (size_t)r * (H_HEADS * 4) + h * 4) = o;
  }
}

// ---------------------------------------------------------------------------
extern "C" void kernel_launch(void* const* d_in, const int* in_sizes, int n_in,
                              void* d_out, int out_size, void* d_ws,
                              size_t ws_size, hipStream_t stream) {
  const float* x        = (const float*)d_in[0];
  const int* row_index  = (const int*)d_in[1];
  const int* col_index  = (const int*)d_in[2];
  const int* to_col     = (const int*)d_in[3];
  const float* att_bias = (const float*)d_in[4];
  const float* dist     = (const float*)d_in[5];
  const float* pos      = (const float*)d_in[6];
  const float* col_pos  = (const float*)d_in[7];
  const float* q_w      = (const float*)d_in[8];
  const float* q_b      = (const float*)d_in[9];
  const float* k_w      = (const float*)d_in[10];
  const float* k_b      = (const float*)d_in[11];
  float* out = (float*)d_out;

  // ws: qh[N*512 f16] | kh[N*512 f16] | wq_h | wk_h | row_start[N+1] | ge[NNZ]
  //     (~69 MB)
  _Float16* qh = (_Float16*)d_ws;
  _Float16* kh = qh + (size_t)N_NODES * 512;
  _Float16* wq_h = kh + (size_t)N_NODES * 512;
  _Float16* wk_h = wq_h + 512 * 512;
  int* row_start = (int*)(wk_h + 512 * 512);
  int* ge = row_start + (N_NODES + 1);

  prep_small<<<256 + NNZ_E / 256, 256, 0, stream>>>(
      q_w, k_w, row_index, col_index, to_col, wq_h, wk_h, row_start, ge);

  gemm_mfma<<<2048, 256, 0, stream>>>(x, wq_h, wk_h, q_b, k_b, qh, kh);

  row_fused<<<N_NODES / 4, 256, 0, stream>>>(qh, kh, row_start, ge, att_bias,
                                             col_index, dist, pos, col_pos,
                                             out);
}

// Round 8
// 268.288 us; speedup vs baseline: 1.0560x; 1.0560x over previous
//
#include <hip/hip_runtime.h>
#include <math.h>
#include <stdint.h>

#define N_NODES 32768
#define E_DIM   512
#define H_HEADS 8
#define D_HEAD  64
#define NNZ_E   524288

typedef __attribute__((ext_vector_type(4))) float f32x4;
typedef __attribute__((ext_vector_type(8))) _Float16 f16x8;  // 8 fp16 = 4 VGPRs

// async 16B global->LDS (wave-uniform LDS base + lane*16)
__device__ __forceinline__ void async16(const void* g, void* l) {
  __builtin_amdgcn_global_load_lds(
      (const __attribute__((address_space(1))) void*)g,
      (__attribute__((address_space(3))) void*)l, 16, 0, 0);
}

// 8-elem fp16 dot accumulated into f32 via v_dot2_f32_f16.
__device__ __forceinline__ float dot8(const f16x8 a, const f16x8 b, float acc) {
#if __has_builtin(__builtin_amdgcn_fdot2)
  acc = __builtin_amdgcn_fdot2(__builtin_shufflevector(a, a, 0, 1),
                               __builtin_shufflevector(b, b, 0, 1), acc, false);
  acc = __builtin_amdgcn_fdot2(__builtin_shufflevector(a, a, 2, 3),
                               __builtin_shufflevector(b, b, 2, 3), acc, false);
  acc = __builtin_amdgcn_fdot2(__builtin_shufflevector(a, a, 4, 5),
                               __builtin_shufflevector(b, b, 4, 5), acc, false);
  acc = __builtin_amdgcn_fdot2(__builtin_shufflevector(a, a, 6, 7),
                               __builtin_shufflevector(b, b, 6, 7), acc, false);
#else
#pragma unroll
  for (int i = 0; i < 8; ++i) acc = fmaf((float)a[i], (float)b[i], acc);
#endif
  return acc;
}

// ---------------------------------------------------------------------------
// prep_small (CSR/ge moved into gemm's grid — see below):
//   blocks [0,128)     : q_w -> fp16 wq_h [512][512]
//   blocks [128,256)   : k_w -> fp16 wk_h
//   blocks [256,8448)  : x   -> fp16 xs   [32768][512]
// The fp16 x pre-split is REQUIRED: round-7 proved consuming fp32 x directly
// in the gemm costs 2x (fp32 LDS tile = 1.5x staging + 4.19M bank conflicts
// + per-fragment cvt chain). This pass is the coalescing/conversion device.
// ---------------------------------------------------------------------------
__global__ __launch_bounds__(256) void prep_small(
    const float* __restrict__ x,
    const float* __restrict__ q_w, const float* __restrict__ k_w,
    _Float16* __restrict__ wq_h, _Float16* __restrict__ wk_h,
    _Float16* __restrict__ xs) {
  const int b = blockIdx.x;
  const float* src;
  _Float16* dst;
  int t;
  if (b < 128)      { src = q_w; dst = wq_h; t = b * 256 + threadIdx.x; }
  else if (b < 256) { src = k_w; dst = wk_h; t = (b - 128) * 256 + threadIdx.x; }
  else              { src = x;   dst = xs;   t = (b - 256) * 256 + threadIdx.x; }
  const int r = t >> 6;            // 64 threads per 512-wide row
  const int c8 = (t & 63) << 3;    // 8 elements per thread
  const float4 v0 = *(const float4*)(src + (size_t)r * 512 + c8);
  const float4 v1 = *(const float4*)(src + (size_t)r * 512 + c8 + 4);
  f16x8 o;
  o[0] = (_Float16)v0.x; o[1] = (_Float16)v0.y;
  o[2] = (_Float16)v0.z; o[3] = (_Float16)v0.w;
  o[4] = (_Float16)v1.x; o[5] = (_Float16)v1.y;
  o[6] = (_Float16)v1.z; o[7] = (_Float16)v1.w;
  *(f16x8*)(dst + (size_t)r * 512 + c8) = o;
}

// ---------------------------------------------------------------------------
// fp16 MFMA GEMM, BK=32, single-buffer 2-barrier loop — the proven ~46 us
// configuration (r5/r6; BK=64 measured equivalent, so barrier amortization
// is already saturated at this K-depth). A and B both pre-split fp16,
// staged with the same r7-swizzle; fragment reads conflict-free.
// Blocks [2048,4096) take the CSR/ge path instead: that work depends only
// on row_index/col_index/to_col (not on prep), feeds only row_fused, and is
// latency-bound — riding it in this grid hides its ~8 us under the gemm's
// staging stalls instead of serializing in prep.
// XCD swizzle (b&7 = panel group) keeps the x panel HBM-once.
// Outputs fp16: qh = (x@qw+qb)/8 (head scale folded), kh = x@kw+kb.
// ---------------------------------------------------------------------------
__global__ __launch_bounds__(256) void gemm_mfma(
    const _Float16* __restrict__ xs,   // [N][512] fp16
    const _Float16* __restrict__ wqh,  // [512][512] fp16
    const _Float16* __restrict__ wkh,
    const float* __restrict__ q_b, const float* __restrict__ k_b,
    _Float16* __restrict__ qh, _Float16* __restrict__ kh,
    const int* __restrict__ row_index, const int* __restrict__ col_index,
    const int* __restrict__ to_col,
    int* __restrict__ row_start, int* __restrict__ ge) {
  __shared__ _Float16 Ah[128 * 32];  // 8 KB each
  __shared__ _Float16 Bh[128 * 32];
  const int b = blockIdx.x;

  if (b >= 2048) {  // CSR/ge rider blocks (wave-uniform branch, no barriers)
    const int e = (b - 2048) * 256 + threadIdx.x;
    if (e < NNZ_E) {
      ge[e] = to_col[col_index[e]];
      const int r0 = row_index[e];
      const int r1 = (e + 1 < NNZ_E) ? row_index[e + 1] : N_NODES;
      if (e == 0)
        for (int r = 0; r <= r0; ++r) row_start[r] = 0;
      for (int r = r0 + 1; r <= r1; ++r) row_start[r] = e + 1;
    }
    return;
  }

  const int tid = threadIdx.x;
  const int w = tid >> 6;        // wave 0..3
  const int l = tid & 63;

  const int j = b >> 3;
  const int mb = (b & 7) * 32 + (j >> 3);
  const int c = j & 7;
  const bool is_q = ((c & 1) == 0);
  const int bm = mb * 128;
  const int bn = (c >> 1) * 128;

  const _Float16* __restrict__ wmat = is_q ? wqh : wkh;
  const float* __restrict__ bias = is_q ? q_b : k_b;
  _Float16* __restrict__ outp = is_q ? qh : kh;
  const float oscale = is_q ? 0.125f : 1.0f;

  const int wm = (w & 1) * 64;   // wave's m-quadrant
  const int wn = (w >> 1) * 64;  // wave's n-quadrant

  f32x4 acc[4][4];
#pragma unroll
  for (int i = 0; i < 4; ++i)
#pragma unroll
    for (int jj = 0; jj < 4; ++jj) acc[i][jj] = (f32x4){0.f, 0.f, 0.f, 0.f};

  // staging map (r7 swizzle): LDS chunk jx of row r holds global chunk
  // jx ^ ((r>>1)&3); lane l covers row w*16+(l>>2), chunk l&3.
  const int sr0 = w * 16 + (l >> 2);
  const int sr1 = sr0 + 64;
  const int sc = (((l & 3) ^ ((l >> 3) & 3)) << 3);
  // fragment map: lane wants row (base + fr), global K-chunk l>>4, stored at
  // chunk (l>>4) ^ ((fr>>1)&3).
  const int fr = l & 15;
  const int fcs = ((((l >> 4) ^ ((fr >> 1) & 3)) & 3) << 3);

  const _Float16* __restrict__ wa = wmat + (size_t)bn * 512;
  const _Float16* __restrict__ xa = xs + (size_t)bm * 512;

  for (int k0 = 0; k0 < 512; k0 += 32) {
    async16(xa + (size_t)sr0 * 512 + k0 + sc, Ah + w * 512);
    async16(xa + (size_t)sr1 * 512 + k0 + sc, Ah + (w + 4) * 512);
    async16(wa + (size_t)sr0 * 512 + k0 + sc, Bh + w * 512);
    async16(wa + (size_t)sr1 * 512 + k0 + sc, Bh + (w + 4) * 512);
    __syncthreads();

    f16x8 av[4], bv[4];
#pragma unroll
    for (int i = 0; i < 4; ++i)
      av[i] = *(const f16x8*)(Ah + (wm + i * 16 + fr) * 32 + fcs);
#pragma unroll
    for (int i = 0; i < 4; ++i)
      bv[i] = *(const f16x8*)(Bh + (wn + i * 16 + fr) * 32 + fcs);
#pragma unroll
    for (int i = 0; i < 4; ++i)
#pragma unroll
      for (int jj = 0; jj < 4; ++jj)
        acc[i][jj] = __builtin_amdgcn_mfma_f32_16x16x32_f16(
            av[i], bv[jj], acc[i][jj], 0, 0, 0);
    __syncthreads();
  }

  // epilogue: C/D layout col = l&15 (n), row = (l>>4)*4 + reg (m); fp16 out
  const int cn = l & 15;
  const int cm4 = (l >> 4) * 4;
  float bvals[4];
#pragma unroll
  for (int jj = 0; jj < 4; ++jj) bvals[jj] = bias[bn + wn + jj * 16 + cn];
#pragma unroll
  for (int i = 0; i < 4; ++i) {
#pragma unroll
    for (int r = 0; r < 4; ++r) {
      const int m = bm + wm + i * 16 + cm4 + r;
      _Float16* op = outp + (size_t)m * 512 + bn + wn + cn;
#pragma unroll
      for (int jj = 0; jj < 4; ++jj) {
        op[jj * 16] = (_Float16)((acc[i][jj][r] + bvals[jj]) * oscale);
      }
    }
  }
}

// ---------------------------------------------------------------------------
// row_fused: CSR row-owned edge logits + online softmax + featurize.
// At its structural floor (~87 us): 512 MB logical k-gather; L2-miss path
// 286 MB @ ~3.3 TB/s (L3 random-access service). Round-6 proved VALU is not
// the limit (halving it changed nothing); occupancy 69%, MLP ample.
// ---------------------------------------------------------------------------
__global__ __launch_bounds__(256) void row_fused(
    const _Float16* __restrict__ qh, const _Float16* __restrict__ kh,
    const int* __restrict__ row_start, const int* __restrict__ ge,
    const float* __restrict__ att_bias, const int* __restrict__ col_index,
    const float* __restrict__ dist, const float* __restrict__ pos,
    const float* __restrict__ col_pos, float* __restrict__ out) {
  const int r = blockIdx.x * 4 + (threadIdx.x >> 6);
  const int lane = threadIdx.x & 63;
  const int h = lane >> 3;
  const int start = row_start[r];
  const int end = row_start[r + 1];

  const f16x8 qv = *(const f16x8*)(qh + (size_t)r * E_DIM + lane * 8);
  const float* __restrict__ biasp = att_bias + (size_t)h * NNZ_E;

  float m = -INFINITY, l = 0.f, accw = 0.f, a0 = 0.f, a1 = 0.f, a2 = 0.f;

  auto edge_logit = [&](const f16x8 kv) -> float {
    float s = dot8(qv, kv, 0.f);
    s += __shfl_xor(s, 1);
    s += __shfl_xor(s, 2);
    s += __shfl_xor(s, 4);
    return s;
  };
  auto upd = [&](float logit, float dd, float c0, float c1, float c2) {
    const float w = (dd == 0.f) ? 0.f : __builtin_amdgcn_rcpf(dd);
    const float nm = fmaxf(m, logit);
    const float sc = __expf(m - nm);
    const float p = __expf(logit - nm);
    m = nm;
    l = fmaf(l, sc, p);
    const float pw = p * w;
    accw = fmaf(accw, sc, pw);
    a0 = fmaf(a0, sc, pw * c0);
    a1 = fmaf(a1, sc, pw * c1);
    a2 = fmaf(a2, sc, pw * c2);
  };

  int e = start;
  for (; e + 4 <= end; e += 4) {
    int g[4], cc[4];
    float dd[4], bb[4], cp[4][3];
    f16x8 kv[4];
#pragma unroll
    for (int i = 0; i < 4; ++i) g[i] = ge[e + i];
#pragma unroll
    for (int i = 0; i < 4; ++i)
      kv[i] = *(const f16x8*)(kh + (size_t)g[i] * E_DIM + lane * 8);
#pragma unroll
    for (int i = 0; i < 4; ++i) {
      cc[i] = col_index[e + i];
      dd[i] = dist[e + i];
      bb[i] = biasp[e + i];
    }
#pragma unroll
    for (int i = 0; i < 4; ++i) {
      cp[i][0] = col_pos[cc[i] * 3 + 0];
      cp[i][1] = col_pos[cc[i] * 3 + 1];
      cp[i][2] = col_pos[cc[i] * 3 + 2];
    }
    float s[4];
#pragma unroll
    for (int i = 0; i < 4; ++i) s[i] = edge_logit(kv[i]) + bb[i];
#pragma unroll
    for (int i = 0; i < 4; ++i) upd(s[i], dd[i], cp[i][0], cp[i][1], cp[i][2]);
  }
  for (; e < end; ++e) {
    const int g0 = ge[e];
    const f16x8 kv0 = *(const f16x8*)(kh + (size_t)g0 * E_DIM + lane * 8);
    const int c0 = col_index[e];
    const float dd0 = dist[e];
    const float bb0 = biasp[e];
    const float cp00 = col_pos[c0 * 3 + 0];
    const float cp01 = col_pos[c0 * 3 + 1];
    const float cp02 = col_pos[c0 * 3 + 2];
    const float s0 = edge_logit(kv0) + bb0;
    upd(s0, dd0, cp00, cp01, cp02);
  }

  if ((lane & 7) == 0) {
    const float invz = (l > 0.f) ? 1.f / l : 0.f;
    const float avg = accw * invz;
    const float v0 = a0 * invz - avg * pos[r * 3 + 0];
    const float v1 = a1 * invz - avg * pos[r * 3 + 1];
    const float v2 = a2 * invz - avg * pos[r * 3 + 2];
    const float nrm = sqrtf(v0 * v0 + v1 * v1 + v2 * v2);
    const float invn = 1.f / fmaxf(nrm, 1e-12f);
    float4 o;
    o.x = v0 * invn; o.y = v1 * invn; o.z = v2 * invn; o.w = avg;
    *(float4*)(out + (size_t)r * (H_HEADS * 4) + h * 4) = o;
  }
}

// ---------------------------------------------------------------------------
extern "C" void kernel_launch(void* const* d_in, const int* in_sizes, int n_in,
                              void* d_out, int out_size, void* d_ws,
                              size_t ws_size, hipStream_t stream) {
  const float* x        = (const float*)d_in[0];
  const int* row_index  = (const int*)d_in[1];
  const int* col_index  = (const int*)d_in[2];
  const int* to_col     = (const int*)d_in[3];
  const float* att_bias = (const float*)d_in[4];
  const float* dist     = (const float*)d_in[5];
  const float* pos      = (const float*)d_in[6];
  const float* col_pos  = (const float*)d_in[7];
  const float* q_w      = (const float*)d_in[8];
  const float* q_b      = (const float*)d_in[9];
  const float* k_w      = (const float*)d_in[10];
  const float* k_b      = (const float*)d_in[11];
  float* out = (float*)d_out;

  // ws: qh[N*512 f16] | kh[N*512 f16] | xs[N*512 f16] | wq_h | wk_h
  //     | row_start[N+1] | ge[NNZ]   (~100 MB)
  _Float16* qh = (_Float16*)d_ws;
  _Float16* kh = qh + (size_t)N_NODES * 512;
  _Float16* xs = kh + (size_t)N_NODES * 512;
  _Float16* wq_h = xs + (size_t)N_NODES * 512;
  _Float16* wk_h = wq_h + 512 * 512;
  int* row_start = (int*)(wk_h + 512 * 512);
  int* ge = row_start + (N_NODES + 1);

  prep_small<<<8448, 256, 0, stream>>>(x, q_w, k_w, wq_h, wk_h, xs);

  // blocks [0,2048): gemm; [2048,4096): CSR/ge rider work
  gemm_mfma<<<4096, 256, 0, stream>>>(xs, wq_h, wk_h, q_b, k_b, qh, kh,
                                      row_index, col_index, to_col,
                                      row_start, ge);

  row_fused<<<N_NODES / 4, 256, 0, stream>>>(qh, kh, row_start, ge, att_bias,
                                             col_index, dist, pos, col_pos,
                                             out);
}

// Round 9
// 261.079 us; speedup vs baseline: 1.0852x; 1.0276x over previous
//
#include <hip/hip_runtime.h>
#include <math.h>
#include <stdint.h>

#define N_NODES 32768
#define E_DIM   512
#define H_HEADS 8
#define D_HEAD  64
#define NNZ_E   524288

typedef __attribute__((ext_vector_type(4))) float f32x4;
typedef __attribute__((ext_vector_type(8))) _Float16 f16x8;  // 8 fp16 = 4 VGPRs

// async 16B global->LDS (wave-uniform LDS base + lane*16)
__device__ __forceinline__ void async16(const void* g, void* l) {
  __builtin_amdgcn_global_load_lds(
      (const __attribute__((address_space(1))) void*)g,
      (__attribute__((address_space(3))) void*)l, 16, 0, 0);
}

// 8-elem fp16 dot accumulated into f32 via v_dot2_f32_f16.
__device__ __forceinline__ float dot8(const f16x8 a, const f16x8 b, float acc) {
#if __has_builtin(__builtin_amdgcn_fdot2)
  acc = __builtin_amdgcn_fdot2(__builtin_shufflevector(a, a, 0, 1),
                               __builtin_shufflevector(b, b, 0, 1), acc, false);
  acc = __builtin_amdgcn_fdot2(__builtin_shufflevector(a, a, 2, 3),
                               __builtin_shufflevector(b, b, 2, 3), acc, false);
  acc = __builtin_amdgcn_fdot2(__builtin_shufflevector(a, a, 4, 5),
                               __builtin_shufflevector(b, b, 4, 5), acc, false);
  acc = __builtin_amdgcn_fdot2(__builtin_shufflevector(a, a, 6, 7),
                               __builtin_shufflevector(b, b, 6, 7), acc, false);
#else
#pragma unroll
  for (int i = 0; i < 8; ++i) acc = fmaf((float)a[i], (float)b[i], acc);
#endif
  return acc;
}

// ---------------------------------------------------------------------------
// prep_small (r6-proven arrangement; CSR rider in gemm was null-to-negative):
//   blocks [0,128)       : q_w -> fp16 wq_h [512][512]
//   blocks [128,256)     : k_w -> fp16 wk_h
//   blocks [256,8448)    : x   -> fp16 xs   [32768][512]
//   blocks [8448,10496)  : ge + CSR row_start
// The fp16 x pre-split is REQUIRED: r7 proved fp32-A staging costs 2x
// (1.5x staging bytes + 4.19M bank conflicts + per-fragment cvt chain).
// ---------------------------------------------------------------------------
__global__ __launch_bounds__(256) void prep_small(
    const float* __restrict__ x,
    const float* __restrict__ q_w, const float* __restrict__ k_w,
    const int* __restrict__ row_index, const int* __restrict__ col_index,
    const int* __restrict__ to_col,
    _Float16* __restrict__ wq_h, _Float16* __restrict__ wk_h,
    _Float16* __restrict__ xs,
    int* __restrict__ row_start, int* __restrict__ ge) {
  const int b = blockIdx.x;
  if (b < 8448) {
    const float* src;
    _Float16* dst;
    int t;
    if (b < 128)      { src = q_w; dst = wq_h; t = b * 256 + threadIdx.x; }
    else if (b < 256) { src = k_w; dst = wk_h; t = (b - 128) * 256 + threadIdx.x; }
    else              { src = x;   dst = xs;   t = (b - 256) * 256 + threadIdx.x; }
    const int r = t >> 6;            // 64 threads per 512-wide row
    const int c8 = (t & 63) << 3;    // 8 elements per thread
    const float4 v0 = *(const float4*)(src + (size_t)r * 512 + c8);
    const float4 v1 = *(const float4*)(src + (size_t)r * 512 + c8 + 4);
    f16x8 o;
    o[0] = (_Float16)v0.x; o[1] = (_Float16)v0.y;
    o[2] = (_Float16)v0.z; o[3] = (_Float16)v0.w;
    o[4] = (_Float16)v1.x; o[5] = (_Float16)v1.y;
    o[6] = (_Float16)v1.z; o[7] = (_Float16)v1.w;
    *(f16x8*)(dst + (size_t)r * 512 + c8) = o;
  } else {
    const int e = (b - 8448) * 256 + threadIdx.x;
    if (e < NNZ_E) {
      ge[e] = to_col[col_index[e]];
      const int r0 = row_index[e];
      const int r1 = (e + 1 < NNZ_E) ? row_index[e + 1] : N_NODES;
      if (e == 0)
        for (int r = 0; r <= r0; ++r) row_start[r] = 0;
      for (int r = r0 + 1; r <= r1; ++r) row_start[r] = e + 1;
    }
  }
}

// ---------------------------------------------------------------------------
// fp16 MFMA GEMM, BK=32, single-buffer 2-barrier loop — the proven r5/r6
// configuration (~46-55 us; BK=64 measured equivalent). A and B both
// pre-split fp16, staged with the same r7-swizzle; fragment reads
// conflict-free. XCD swizzle (b&7 = panel group) keeps the x panel HBM-once.
// Outputs fp16: qh = (x@qw+qb)/8 (head scale folded), kh = x@kw+kb.
// ---------------------------------------------------------------------------
__global__ __launch_bounds__(256) void gemm_mfma(
    const _Float16* __restrict__ xs,   // [N][512] fp16
    const _Float16* __restrict__ wqh,  // [512][512] fp16
    const _Float16* __restrict__ wkh,
    const float* __restrict__ q_b, const float* __restrict__ k_b,
    _Float16* __restrict__ qh, _Float16* __restrict__ kh) {
  __shared__ _Float16 Ah[128 * 32];  // 8 KB each
  __shared__ _Float16 Bh[128 * 32];
  const int tid = threadIdx.x;
  const int w = tid >> 6;        // wave 0..3
  const int l = tid & 63;

  const int b = blockIdx.x;
  const int j = b >> 3;
  const int mb = (b & 7) * 32 + (j >> 3);
  const int c = j & 7;
  const bool is_q = ((c & 1) == 0);
  const int bm = mb * 128;
  const int bn = (c >> 1) * 128;

  const _Float16* __restrict__ wmat = is_q ? wqh : wkh;
  const float* __restrict__ bias = is_q ? q_b : k_b;
  _Float16* __restrict__ outp = is_q ? qh : kh;
  const float oscale = is_q ? 0.125f : 1.0f;

  const int wm = (w & 1) * 64;   // wave's m-quadrant
  const int wn = (w >> 1) * 64;  // wave's n-quadrant

  f32x4 acc[4][4];
#pragma unroll
  for (int i = 0; i < 4; ++i)
#pragma unroll
    for (int jj = 0; jj < 4; ++jj) acc[i][jj] = (f32x4){0.f, 0.f, 0.f, 0.f};

  // staging map (r7 swizzle): LDS chunk jx of row r holds global chunk
  // jx ^ ((r>>1)&3); lane l covers row w*16+(l>>2), chunk l&3.
  const int sr0 = w * 16 + (l >> 2);
  const int sr1 = sr0 + 64;
  const int sc = (((l & 3) ^ ((l >> 3) & 3)) << 3);
  // fragment map: lane wants row (base + fr), global K-chunk l>>4, stored at
  // chunk (l>>4) ^ ((fr>>1)&3).
  const int fr = l & 15;
  const int fcs = ((((l >> 4) ^ ((fr >> 1) & 3)) & 3) << 3);

  const _Float16* __restrict__ wa = wmat + (size_t)bn * 512;
  const _Float16* __restrict__ xa = xs + (size_t)bm * 512;

  for (int k0 = 0; k0 < 512; k0 += 32) {
    async16(xa + (size_t)sr0 * 512 + k0 + sc, Ah + w * 512);
    async16(xa + (size_t)sr1 * 512 + k0 + sc, Ah + (w + 4) * 512);
    async16(wa + (size_t)sr0 * 512 + k0 + sc, Bh + w * 512);
    async16(wa + (size_t)sr1 * 512 + k0 + sc, Bh + (w + 4) * 512);
    __syncthreads();

    f16x8 av[4], bv[4];
#pragma unroll
    for (int i = 0; i < 4; ++i)
      av[i] = *(const f16x8*)(Ah + (wm + i * 16 + fr) * 32 + fcs);
#pragma unroll
    for (int i = 0; i < 4; ++i)
      bv[i] = *(const f16x8*)(Bh + (wn + i * 16 + fr) * 32 + fcs);
#pragma unroll
    for (int i = 0; i < 4; ++i)
#pragma unroll
      for (int jj = 0; jj < 4; ++jj)
        acc[i][jj] = __builtin_amdgcn_mfma_f32_16x16x32_f16(
            av[i], bv[jj], acc[i][jj], 0, 0, 0);
    __syncthreads();
  }

  // epilogue: C/D layout col = l&15 (n), row = (l>>4)*4 + reg (m); fp16 out
  const int cn = l & 15;
  const int cm4 = (l >> 4) * 4;
  float bvals[4];
#pragma unroll
  for (int jj = 0; jj < 4; ++jj) bvals[jj] = bias[bn + wn + jj * 16 + cn];
#pragma unroll
  for (int i = 0; i < 4; ++i) {
#pragma unroll
    for (int r = 0; r < 4; ++r) {
      const int m = bm + wm + i * 16 + cm4 + r;
      _Float16* op = outp + (size_t)m * 512 + bn + wn + cn;
#pragma unroll
      for (int jj = 0; jj < 4; ++jj) {
        op[jj * 16] = (_Float16)((acc[i][jj][r] + bvals[jj]) * oscale);
      }
    }
  }
}

// ---------------------------------------------------------------------------
// row_fused v2: CSR row-owned, DOUBLE-BUFFERED 4-edge gather pipeline.
// Round-8 accounting: ~2250 cyc/edge with no pipe saturated (VALU 46%,
// L2 6/34.5 TB/s, fabric 3.3 TB/s) -> the k-gather's L2-miss latency
// (~500-700 cyc, 56% miss to L3) was EXPOSED once per 4-edge group.
// Now: issue group i+1's four k-row gathers BEFORE processing group i —
// miss latency hides under the previous group's dots/upds + wave TLP.
// Numeric order of dot/upd is IDENTICAL to r6 (same groups, same order):
// absmax must stay 0.0078125. kA/kB = 16 VGPR each; target total <=64.
// ---------------------------------------------------------------------------
__global__ __launch_bounds__(256) void row_fused(
    const _Float16* __restrict__ qh, const _Float16* __restrict__ kh,
    const int* __restrict__ row_start, const int* __restrict__ ge,
    const float* __restrict__ att_bias, const int* __restrict__ col_index,
    const float* __restrict__ dist, const float* __restrict__ pos,
    const float* __restrict__ col_pos, float* __restrict__ out) {
  const int r = blockIdx.x * 4 + (threadIdx.x >> 6);
  const int lane = threadIdx.x & 63;
  const int h = lane >> 3;
  const int start = row_start[r];
  const int end = row_start[r + 1];

  const f16x8 qv = *(const f16x8*)(qh + (size_t)r * E_DIM + lane * 8);
  const float* __restrict__ biasp = att_bias + (size_t)h * NNZ_E;

  float m = -INFINITY, l = 0.f, accw = 0.f, a0 = 0.f, a1 = 0.f, a2 = 0.f;

  auto edge_logit = [&](const f16x8 kv) -> float {
    float s = dot8(qv, kv, 0.f);
    s += __shfl_xor(s, 1);
    s += __shfl_xor(s, 2);
    s += __shfl_xor(s, 4);
    return s;
  };
  auto upd = [&](float logit, float dd, float c0, float c1, float c2) {
    const float w = (dd == 0.f) ? 0.f : __builtin_amdgcn_rcpf(dd);
    const float nm = fmaxf(m, logit);
    const float sc = __expf(m - nm);
    const float p = __expf(logit - nm);
    m = nm;
    l = fmaf(l, sc, p);
    const float pw = p * w;
    accw = fmaf(accw, sc, pw);
    a0 = fmaf(a0, sc, pw * c0);
    a1 = fmaf(a1, sc, pw * c1);
    a2 = fmaf(a2, sc, pw * c2);
  };

  // issue the 4 k-row gathers of the group at e0 into kv[] (no waits here)
  auto loadg = [&](int e0, f16x8* kv) {
#pragma unroll
    for (int i = 0; i < 4; ++i) {
      const int g = ge[e0 + i];
      kv[i] = *(const f16x8*)(kh + (size_t)g * E_DIM + lane * 8);
    }
  };
  // process a group whose k rows are resident in kv[] (same op order as r6)
  auto proc4 = [&](int e0, const f16x8* kv) {
    float dd[4], bb[4];
    int cc[4];
#pragma unroll
    for (int i = 0; i < 4; ++i) {
      cc[i] = col_index[e0 + i];
      dd[i] = dist[e0 + i];
      bb[i] = biasp[e0 + i];
    }
    float s[4];
#pragma unroll
    for (int i = 0; i < 4; ++i) s[i] = edge_logit(kv[i]) + bb[i];
#pragma unroll
    for (int i = 0; i < 4; ++i) {
      const float c0 = col_pos[cc[i] * 3 + 0];
      const float c1 = col_pos[cc[i] * 3 + 1];
      const float c2 = col_pos[cc[i] * 3 + 2];
      upd(s[i], dd[i], c0, c1, c2);
    }
  };

  f16x8 kA[4], kB[4];
  int e = start;
  const int n4 = (end - start) >> 2;
  int gi = 0;
  if (n4 > 0) loadg(e, kA);
  // steady state: kB gathers in flight while kA group computes (and vice
  // versa) — named buffers + 2-group unroll keep all indices compile-time
  // (rule #20: no runtime-indexed reg arrays).
  for (; gi + 2 <= n4; gi += 2, e += 8) {
    loadg(e + 4, kB);
    proc4(e, kA);
    if (gi + 2 < n4) loadg(e + 8, kA);
    proc4(e + 4, kB);
  }
  if (gi < n4) {  // odd leftover full group (already loaded in kA)
    proc4(e, kA);
    e += 4;
  }
  for (; e < end; ++e) {  // 0-3 tail edges
    const int g0 = ge[e];
    const f16x8 kv0 = *(const f16x8*)(kh + (size_t)g0 * E_DIM + lane * 8);
    const int c0 = col_index[e];
    const float dd0 = dist[e];
    const float bb0 = biasp[e];
    const float cp00 = col_pos[c0 * 3 + 0];
    const float cp01 = col_pos[c0 * 3 + 1];
    const float cp02 = col_pos[c0 * 3 + 2];
    const float s0 = edge_logit(kv0) + bb0;
    upd(s0, dd0, cp00, cp01, cp02);
  }

  if ((lane & 7) == 0) {
    const float invz = (l > 0.f) ? 1.f / l : 0.f;
    const float avg = accw * invz;
    const float v0 = a0 * invz - avg * pos[r * 3 + 0];
    const float v1 = a1 * invz - avg * pos[r * 3 + 1];
    const float v2 = a2 * invz - avg * pos[r * 3 + 2];
    const float nrm = sqrtf(v0 * v0 + v1 * v1 + v2 * v2);
    const float invn = 1.f / fmaxf(nrm, 1e-12f);
    float4 o;
    o.x = v0 * invn; o.y = v1 * invn; o.z = v2 * invn; o.w = avg;
    *(float4*)(out + (size_t)r * (H_HEADS * 4) + h * 4) = o;
  }
}

// ---------------------------------------------------------------------------
extern "C" void kernel_launch(void* const* d_in, const int* in_sizes, int n_in,
                              void* d_out, int out_size, void* d_ws,
                              size_t ws_size, hipStream_t stream) {
  const float* x        = (const float*)d_in[0];
  const int* row_index  = (const int*)d_in[1];
  const int* col_index  = (const int*)d_in[2];
  const int* to_col     = (const int*)d_in[3];
  const float* att_bias = (const float*)d_in[4];
  const float* dist     = (const float*)d_in[5];
  const float* pos      = (const float*)d_in[6];
  const float* col_pos  = (const float*)d_in[7];
  const float* q_w      = (const float*)d_in[8];
  const float* q_b      = (const float*)d_in[9];
  const float* k_w      = (const float*)d_in[10];
  const float* k_b      = (const float*)d_in[11];
  float* out = (float*)d_out;

  // ws: qh[N*512 f16] | kh[N*512 f16] | xs[N*512 f16] | wq_h | wk_h
  //     | row_start[N+1] | ge[NNZ]   (~100 MB)
  _Float16* qh = (_Float16*)d_ws;
  _Float16* kh = qh + (size_t)N_NODES * 512;
  _Float16* xs = kh + (size_t)N_NODES * 512;
  _Float16* wq_h = xs + (size_t)N_NODES * 512;
  _Float16* wk_h = wq_h + 512 * 512;
  int* row_start = (int*)(wk_h + 512 * 512);
  int* ge = row_start + (N_NODES + 1);

  prep_small<<<8448 + NNZ_E / 256, 256, 0, stream>>>(
      x, q_w, k_w, row_index, col_index, to_col, wq_h, wk_h, xs, row_start, ge);

  gemm_mfma<<<2048, 256, 0, stream>>>(xs, wq_h, wk_h, q_b, k_b, qh, kh);

  row_fused<<<N_NODES / 4, 256, 0, stream>>>(qh, kh, row_start, ge, att_bias,
                                             col_index, dist, pos, col_pos,
                                             out);
}